// Round 1
// baseline (727.359 us; speedup 1.0000x reference)
//
#include <hip/hip_runtime.h>

#define INV_SQRT2 0.7071067811865476f

// Main pass: one block handles `rowsPerBlock` consecutive rows.
// Per row: stage the 2048-float row into LDS (coalesced float4), then
// threads j = tid, tid+256 (< D) compute the per-(row,j) terms.
// Moments (c_r, c_r^2, c_i, c_i^2) are accumulated grid-strided in the
// same kernel (final combine is linear in the moments).
// ws layout (8 floats): 0:P0  1:P1r  2:P1i  3:P2  4:s_cr 5:s_cr2 6:s_ci 7:s_ci2
__global__ __launch_bounds__(256) void isi_main(
    const float* __restrict__ dnn,
    const float* __restrict__ b,
    const float* __restrict__ h,
    const float* __restrict__ xr,
    const float* __restrict__ xi,
    const float* __restrict__ sym_r,
    const float* __restrict__ sym_i,
    const float* __restrict__ chan,
    const float* __restrict__ noise,
    const float* __restrict__ prob,
    float* __restrict__ ws,
    int B, int P, int D, int MU, int cbase, int midT, int rowsPerBlock)
{
    extern __shared__ float srow[];      // P floats (one dnn_out row)
    __shared__ float red[8][4];          // 8 sums x 4 waves

    const int tid  = threadIdx.x;
    const int wave = tid >> 6;
    const int lane = tid & 63;

    float a0 = 0.f, a1 = 0.f, a2 = 0.f, a3 = 0.f;   // P0, P1r, P1i, P2
    float m0 = 0.f, m1 = 0.f, m2 = 0.f, m3 = 0.f;   // moment sums

    // ---- moments, grid-strided over all B rows (cheap: ~5 MB traffic) ----
    {
        const int gid = blockIdx.x * blockDim.x + tid;
        const int tot = gridDim.x * blockDim.x;
        const int st  = MU - 1;                      // row stride of ISI arrays
        for (int i = gid; i < B; i += tot) {
            float ch = chan[(size_t)i * st];
            float cr = ch * sym_r[(size_t)i * st];
            float ci = ch * sym_i[(size_t)i * st];
            m0 += cr; m1 += cr * cr; m2 += ci; m3 += ci * ci;
        }
    }

    // ---- main pass over this block's rows ----
    const int row0 = blockIdx.x * rowsPerBlock;
    const int row1 = min(B, row0 + rowsPerBlock);
    const int P4   = P >> 2;

    for (int row = row0; row < row1; ++row) {
        // stage row into LDS, coalesced float4
        const float4* g4 = (const float4*)(dnn + (size_t)row * (size_t)P);
        float4* s4 = (float4*)srow;
        for (int c = tid; c < P4; c += 256) s4[c] = g4[c];
        __syncthreads();

        const float bb   = b[row];
        const float bh   = bb * h[row];
        const float vxr  = xr[row];
        const float vxi  = xi[row];
        const float nz   = INV_SQRT2 * noise[row];
        const float bhxr = bh * vxr;
        const float bhxi = bh * vxi;

        for (int j = tid; j < D; j += 256) {
            float sum7 = 0.f;
            const int c = cbase + j;
            for (int k = 0; k < MU; ++k) sum7 += srow[c + k * D];
            const float d0 = srow[midT + j];
            const float S  = sum7 - d0;
            const float Ar = bhxr * d0 + nz - vxr;
            const float Ai = bhxi * d0 + nz - vxi;
            const float bS = bb * S;
            const float pj = prob[midT + j];        // 8 KB, L1-resident
            a0 += pj * (Ar * Ar + Ai * Ai);
            a1 += pj * (Ar * bS);
            a2 += pj * (Ai * bS);
            a3 += pj * (bS * bS);
        }
        __syncthreads();   // protect srow before next row's staging
    }

    // ---- block reduction: 8 sums, wave shuffle then cross-wave via LDS ----
    float v[8] = {a0, a1, a2, a3, m0, m1, m2, m3};
#pragma unroll
    for (int s = 0; s < 8; ++s) {
        float x = v[s];
#pragma unroll
        for (int off = 32; off > 0; off >>= 1) x += __shfl_down(x, off, 64);
        if (lane == 0) red[s][wave] = x;
    }
    __syncthreads();
    if (tid < 8) {
        float x = red[tid][0] + red[tid][1] + red[tid][2] + red[tid][3];
        atomicAdd(&ws[tid], x);
    }
}

__global__ void isi_final(const float* __restrict__ ws,
                          float* __restrict__ out, int B)
{
    const float invB = 1.0f / (float)B;
    const float P0  = ws[0], P1r = ws[1], P1i = ws[2], P2 = ws[3];
    const float m1r = ws[4] * invB, m2r = ws[5] * invB;
    const float m1i = ws[6] * invB, m2i = ws[7] * invB;
    out[0] = (P0 + 2.0f * (m1r * P1r + m1i * P1i) + (m2r + m2i) * P2) * invB;
}

extern "C" void kernel_launch(void* const* d_in, const int* in_sizes, int n_in,
                              void* d_out, int out_size, void* d_ws, size_t ws_size,
                              hipStream_t stream)
{
    const float* dnn   = (const float*)d_in[0];
    const float* b     = (const float*)d_in[1];
    const float* h     = (const float*)d_in[2];
    const float* xr    = (const float*)d_in[3];
    const float* xi    = (const float*)d_in[4];
    const float* sym_r = (const float*)d_in[5];
    const float* sym_i = (const float*)d_in[6];
    const float* chan  = (const float*)d_in[7];
    const float* noise = (const float*)d_in[8];
    const float* prob  = (const float*)d_in[9];

    const int B  = in_sizes[1];                // 65536
    const int P  = in_sizes[0] / B;            // 2048
    const int MU = in_sizes[5] / B + 1;        // 7

    const int T      = (P / MU) / 2;           // 146
    const int D      = 2 * T;                  // 292
    const int mid    = P / 2;                  // 1024
    const int midT   = mid - T;                // 878 (d0 / prob column base)
    const int numISI = MU / 2;                 // 3
    const int cbase  = midT - numISI * D;      // 2  (k=0 column base)

    const int rowsPerBlock = 32;
    const int grid = (B + rowsPerBlock - 1) / rowsPerBlock;   // 2048

    hipMemsetAsync(d_ws, 0, 8 * sizeof(float), stream);

    isi_main<<<grid, 256, P * (int)sizeof(float), stream>>>(
        dnn, b, h, xr, xi, sym_r, sym_i, chan, noise, prob,
        (float*)d_ws, B, P, D, MU, cbase, midT, rowsPerBlock);

    isi_final<<<1, 1, 0, stream>>>((const float*)d_ws, (float*)d_out, B);
}

// Round 2
// 725.824 us; speedup vs baseline: 1.0021x; 1.0021x over previous
//
#include <hip/hip_runtime.h>

#define INV_SQRT2 0.7071067811865476f

// ---------------------------------------------------------------------------
// Fast path: specialized for P=2048, MU=7 (D=292, cbase=2, midT=878).
// One block = 320 threads (5 waves) handles ROWS consecutive rows.
// Thread j (<292) computes the j-term for each row via 7 DIRECT coalesced
// global loads (lane-consecutive addresses). d0 IS the k=3 term; prob[midT+j]
// is row-invariant and hoisted. No LDS staging, no per-row barriers.
// Moments are accumulated grid-strided in the same kernel (the final scalar
// is linear in the moments, so they decouple).
// Per-block partials -> ws[blk*8 + s]  (s: 0:P0 1:P1r 2:P1i 3:P2 4..7 moment sums)
// ---------------------------------------------------------------------------
__global__ __launch_bounds__(320) void isi_main_fast(
    const float* __restrict__ dnn,
    const float* __restrict__ b,
    const float* __restrict__ h,
    const float* __restrict__ xr,
    const float* __restrict__ xi,
    const float* __restrict__ sym_r,
    const float* __restrict__ sym_i,
    const float* __restrict__ chan,
    const float* __restrict__ noise,
    const float* __restrict__ prob,
    float* __restrict__ ws,
    int B, int rowsPerBlock)
{
    constexpr int P = 2048, D = 292, cbase = 2, midT = 878;

    const int tid = threadIdx.x;
    float a0 = 0.f, a1 = 0.f, a2 = 0.f, a3 = 0.f;   // P0, P1r, P1i, P2
    float m0 = 0.f, m1 = 0.f, m2 = 0.f, m3 = 0.f;   // moment sums

    // ---- moments, grid-strided (ISI arrays ~4.5 MB touched, cheap) ----
    {
        const int gid = blockIdx.x * 320 + tid;
        const int tot = gridDim.x * 320;
        for (int i = gid; i < B; i += tot) {
            const float ch = chan[(size_t)i * 6];
            const float cr = ch * sym_r[(size_t)i * 6];
            const float ci = ch * sym_i[(size_t)i * 6];
            m0 += cr; m1 += cr * cr; m2 += ci; m3 += ci * ci;
        }
    }

    // ---- main pass ----
    const int  row0 = blockIdx.x * rowsPerBlock;
    const int  row1 = min(B, row0 + rowsPerBlock);
    const bool act  = (tid < D);
    const float pj  = act ? prob[midT + tid] : 0.f;

#pragma unroll 2
    for (int row = row0; row < row1; ++row) {
        const float* __restrict__ rp = dnn + (size_t)row * P;
        const float bb  = b[row];                 // uniform -> scalar loads
        const float bh  = bb * h[row];
        const float vxr = xr[row];
        const float vxi = xi[row];
        const float nz  = INV_SQRT2 * noise[row];
        const float cr0 = bh * vxr, ar_c = nz - vxr;
        const float ci0 = bh * vxi, ai_c = nz - vxi;

        if (act) {
            const float t0 = rp[cbase + 0 * D + tid];
            const float t1 = rp[cbase + 1 * D + tid];
            const float t2 = rp[cbase + 2 * D + tid];
            const float d0 = rp[cbase + 3 * D + tid];   // == midT + tid
            const float t4 = rp[cbase + 4 * D + tid];
            const float t5 = rp[cbase + 5 * D + tid];
            const float t6 = rp[cbase + 6 * D + tid];

            const float S  = t0 + t1 + t2 + t4 + t5 + t6;   // sum7 - d0
            const float Ar = cr0 * d0 + ar_c;
            const float Ai = ci0 * d0 + ai_c;
            const float bS = bb * S;
            a0 += pj * (Ar * Ar + Ai * Ai);
            a1 += pj * (Ar * bS);
            a2 += pj * (Ai * bS);
            a3 += pj * (bS * bS);
        }
    }

    // ---- block reduction: 8 sums across 5 waves ----
    __shared__ float red[8][5];
    float v[8] = {a0, a1, a2, a3, m0, m1, m2, m3};
    const int wave = tid >> 6, lane = tid & 63;
#pragma unroll
    for (int s = 0; s < 8; ++s) {
        float x = v[s];
#pragma unroll
        for (int off = 32; off > 0; off >>= 1) x += __shfl_down(x, off, 64);
        if (lane == 0) red[s][wave] = x;
    }
    __syncthreads();
    if (tid < 8) {
        float x = red[tid][0] + red[tid][1] + red[tid][2]
                + red[tid][3] + red[tid][4];
        ws[(size_t)blockIdx.x * 8 + tid] = x;
    }
}

// ---------------------------------------------------------------------------
// Generic fallback (runtime P/D/MU), same direct-load structure, block=256.
// ---------------------------------------------------------------------------
__global__ __launch_bounds__(256) void isi_main_generic(
    const float* __restrict__ dnn,
    const float* __restrict__ b,
    const float* __restrict__ h,
    const float* __restrict__ xr,
    const float* __restrict__ xi,
    const float* __restrict__ sym_r,
    const float* __restrict__ sym_i,
    const float* __restrict__ chan,
    const float* __restrict__ noise,
    const float* __restrict__ prob,
    float* __restrict__ ws,
    int B, int P, int D, int MU, int cbase, int midT, int rowsPerBlock)
{
    const int tid = threadIdx.x;
    float a0 = 0.f, a1 = 0.f, a2 = 0.f, a3 = 0.f;
    float m0 = 0.f, m1 = 0.f, m2 = 0.f, m3 = 0.f;
    const int st = MU - 1;
    {
        const int gid = blockIdx.x * 256 + tid;
        const int tot = gridDim.x * 256;
        for (int i = gid; i < B; i += tot) {
            const float ch = chan[(size_t)i * st];
            const float cr = ch * sym_r[(size_t)i * st];
            const float ci = ch * sym_i[(size_t)i * st];
            m0 += cr; m1 += cr * cr; m2 += ci; m3 += ci * ci;
        }
    }
    const int row0 = blockIdx.x * rowsPerBlock;
    const int row1 = min(B, row0 + rowsPerBlock);
    const int nISI = MU / 2;

    for (int row = row0; row < row1; ++row) {
        const float* __restrict__ rp = dnn + (size_t)row * P;
        const float bb  = b[row];
        const float bh  = bb * h[row];
        const float vxr = xr[row];
        const float vxi = xi[row];
        const float nz  = INV_SQRT2 * noise[row];
        const float cr0 = bh * vxr, ar_c = nz - vxr;
        const float ci0 = bh * vxi, ai_c = nz - vxi;
        for (int j = tid; j < D; j += 256) {
            float sum7 = 0.f, d0 = 0.f;
            for (int k = 0; k < MU; ++k) {
                const float t = rp[cbase + k * D + j];
                sum7 += t;
                if (k == nISI) d0 = t;
            }
            const float S  = sum7 - d0;
            const float Ar = cr0 * d0 + ar_c;
            const float Ai = ci0 * d0 + ai_c;
            const float bS = bb * S;
            const float pj = prob[midT + j];
            a0 += pj * (Ar * Ar + Ai * Ai);
            a1 += pj * (Ar * bS);
            a2 += pj * (Ai * bS);
            a3 += pj * (bS * bS);
        }
    }

    __shared__ float red[8][4];
    float v[8] = {a0, a1, a2, a3, m0, m1, m2, m3};
    const int wave = tid >> 6, lane = tid & 63;
#pragma unroll
    for (int s = 0; s < 8; ++s) {
        float x = v[s];
#pragma unroll
        for (int off = 32; off > 0; off >>= 1) x += __shfl_down(x, off, 64);
        if (lane == 0) red[s][wave] = x;
    }
    __syncthreads();
    if (tid < 8) {
        float x = red[tid][0] + red[tid][1] + red[tid][2] + red[tid][3];
        ws[(size_t)blockIdx.x * 8 + tid] = x;
    }
}

// ---------------------------------------------------------------------------
// Final: one wave reduces nblk partial-slot vectors and combines.
// out = (P0 + 2(m1r P1r + m1i P1i) + (m2r + m2i) P2) / B, moments = sums/B.
// ---------------------------------------------------------------------------
__global__ void isi_final(const float* __restrict__ ws,
                          float* __restrict__ out, int nblk, int B)
{
    const int lane = threadIdx.x;      // 64 threads
    float v[8] = {0.f, 0.f, 0.f, 0.f, 0.f, 0.f, 0.f, 0.f};
    for (int i = lane; i < nblk; i += 64) {
        const float* p = ws + (size_t)i * 8;
#pragma unroll
        for (int s = 0; s < 8; ++s) v[s] += p[s];
    }
#pragma unroll
    for (int s = 0; s < 8; ++s) {
        float x = v[s];
#pragma unroll
        for (int off = 32; off > 0; off >>= 1) x += __shfl_down(x, off, 64);
        v[s] = x;
    }
    if (lane == 0) {
        const float invB = 1.0f / (float)B;
        const float P0 = v[0], P1r = v[1], P1i = v[2], P2 = v[3];
        const float m1r = v[4] * invB, m2r = v[5] * invB;
        const float m1i = v[6] * invB, m2i = v[7] * invB;
        out[0] = (P0 + 2.0f * (m1r * P1r + m1i * P1i)
                  + (m2r + m2i) * P2) * invB;
    }
}

extern "C" void kernel_launch(void* const* d_in, const int* in_sizes, int n_in,
                              void* d_out, int out_size, void* d_ws, size_t ws_size,
                              hipStream_t stream)
{
    const float* dnn   = (const float*)d_in[0];
    const float* b     = (const float*)d_in[1];
    const float* h     = (const float*)d_in[2];
    const float* xr    = (const float*)d_in[3];
    const float* xi    = (const float*)d_in[4];
    const float* sym_r = (const float*)d_in[5];
    const float* sym_i = (const float*)d_in[6];
    const float* chan  = (const float*)d_in[7];
    const float* noise = (const float*)d_in[8];
    const float* prob  = (const float*)d_in[9];

    const int B  = in_sizes[1];                // 65536
    const int P  = in_sizes[0] / B;            // 2048
    const int MU = in_sizes[5] / B + 1;        // 7

    const int T     = (P / MU) / 2;            // 146
    const int D     = 2 * T;                   // 292
    const int mid   = P / 2;
    const int midT  = mid - T;                 // 878
    const int cbase = midT - (MU / 2) * D;     // 2

    const int rowsPerBlock = 16;
    const int grid = (B + rowsPerBlock - 1) / rowsPerBlock;   // 4096

    if (P == 2048 && MU == 7 && D == 292 && cbase == 2 && midT == 878) {
        isi_main_fast<<<grid, 320, 0, stream>>>(
            dnn, b, h, xr, xi, sym_r, sym_i, chan, noise, prob,
            (float*)d_ws, B, rowsPerBlock);
    } else {
        isi_main_generic<<<grid, 256, 0, stream>>>(
            dnn, b, h, xr, xi, sym_r, sym_i, chan, noise, prob,
            (float*)d_ws, B, P, D, MU, cbase, midT, rowsPerBlock);
    }
    isi_final<<<1, 64, 0, stream>>>((const float*)d_ws, (float*)d_out, grid, B);
}

// Round 4
// 688.930 us; speedup vs baseline: 1.0558x; 1.0536x over previous
//
#include <hip/hip_runtime.h>

#define INV_SQRT2 0.7071067811865476f

typedef float f32x4 __attribute__((ext_vector_type(4)));   // native vec for nontemporal builtins

// ---------------------------------------------------------------------------
// Fast path, specialized for P=2048, MU=7 (D=292, cbase=2, midT=878).
// Block = 320 threads = 4 groups x 80. Group g owns row (rowBase + g);
// thread jv = tid%80 (<73 active) owns 4 consecutive columns j = 4*jv..+3.
// Per (row, thread): 7 nontemporal float4 loads (k-terms, lane-contiguous
// 1168B segments). d0 IS the k=3 term. prob is row-invariant, hoisted.
// Moments accumulated grid-strided in-kernel (final scalar is linear in them).
// Per-block partials -> ws[blk*8 + s] (0:P0 1:P1r 2:P1i 3:P2 4..7 moments).
// ---------------------------------------------------------------------------
__global__ __launch_bounds__(320) void isi_main_fast(
    const float* __restrict__ dnn,
    const float* __restrict__ b,
    const float* __restrict__ h,
    const float* __restrict__ xr,
    const float* __restrict__ xi,
    const float* __restrict__ sym_r,
    const float* __restrict__ sym_i,
    const float* __restrict__ chan,
    const float* __restrict__ noise,
    const float* __restrict__ prob,
    float* __restrict__ ws,
    int B, int rowsPerBlock)
{
    constexpr int P = 2048, D = 292, cbase = 2, midT = 878;

    const int tid = threadIdx.x;
    float a0 = 0.f, a1 = 0.f, a2 = 0.f, a3 = 0.f;   // P0, P1r, P1i, P2
    float m0 = 0.f, m1 = 0.f, m2 = 0.f, m3 = 0.f;   // moment sums

    // ---- moments, grid-strided (~4.7 MB total, negligible) ----
    {
        const int gid = blockIdx.x * 320 + tid;
        const int tot = gridDim.x * 320;
        for (int i = gid; i < B; i += tot) {
            const float ch = chan[(size_t)i * 6];
            const float cr = ch * sym_r[(size_t)i * 6];
            const float ci = ch * sym_i[(size_t)i * 6];
            m0 += cr; m1 += cr * cr; m2 += ci; m3 += ci * ci;
        }
    }

    // ---- main pass ----
    const int g  = tid / 80;           // row sub-index within 4-row step
    const int jv = tid % 80;           // column-quad index
    const bool act = (jv < 73);
    const int  j0  = 4 * jv;           // first of this thread's 4 columns

    f32x4 pj = (f32x4)(0.f);
    if (act) pj = *(const f32x4*)(prob + midT + j0);

    const int row0 = blockIdx.x * rowsPerBlock;

#pragma unroll 2
    for (int r = 0; r < rowsPerBlock; r += 4) {
        const int row = row0 + r + g;
        const float* __restrict__ rp = dnn + (size_t)row * P + cbase + j0;

        const float bb  = b[row];
        const float bh  = bb * h[row];
        const float vxr = xr[row];
        const float vxi = xi[row];
        const float nz  = INV_SQRT2 * noise[row];
        const float cr0 = bh * vxr, ar_c = nz - vxr;
        const float ci0 = bh * vxi, ai_c = nz - vxi;

        if (act) {
            const f32x4 t0 = __builtin_nontemporal_load((const f32x4*)(rp + 0 * D));
            const f32x4 t1 = __builtin_nontemporal_load((const f32x4*)(rp + 1 * D));
            const f32x4 t2 = __builtin_nontemporal_load((const f32x4*)(rp + 2 * D));
            const f32x4 d0 = __builtin_nontemporal_load((const f32x4*)(rp + 3 * D));
            const f32x4 t4 = __builtin_nontemporal_load((const f32x4*)(rp + 4 * D));
            const f32x4 t5 = __builtin_nontemporal_load((const f32x4*)(rp + 5 * D));
            const f32x4 t6 = __builtin_nontemporal_load((const f32x4*)(rp + 6 * D));

            const f32x4 S = t0 + t1 + t2 + t4 + t5 + t6;   // sum7 - d0

#pragma unroll
            for (int c = 0; c < 4; ++c) {
                const float Ar = cr0 * d0[c] + ar_c;
                const float Ai = ci0 * d0[c] + ai_c;
                const float bS = bb * S[c];
                const float p  = pj[c];
                a0 += p * (Ar * Ar + Ai * Ai);
                a1 += p * (Ar * bS);
                a2 += p * (Ai * bS);
                a3 += p * (bS * bS);
            }
        }
    }

    // ---- block reduction: 8 sums across 5 waves ----
    __shared__ float red[8][5];
    float v[8] = {a0, a1, a2, a3, m0, m1, m2, m3};
    const int wave = tid >> 6, lane = tid & 63;
#pragma unroll
    for (int s = 0; s < 8; ++s) {
        float x = v[s];
#pragma unroll
        for (int off = 32; off > 0; off >>= 1) x += __shfl_down(x, off, 64);
        if (lane == 0) red[s][wave] = x;
    }
    __syncthreads();
    if (tid < 8) {
        float x = red[tid][0] + red[tid][1] + red[tid][2]
                + red[tid][3] + red[tid][4];
        ws[(size_t)blockIdx.x * 8 + tid] = x;
    }
}

// ---------------------------------------------------------------------------
// Generic fallback (runtime P/D/MU), direct-load structure, block=256.
// ---------------------------------------------------------------------------
__global__ __launch_bounds__(256) void isi_main_generic(
    const float* __restrict__ dnn,
    const float* __restrict__ b,
    const float* __restrict__ h,
    const float* __restrict__ xr,
    const float* __restrict__ xi,
    const float* __restrict__ sym_r,
    const float* __restrict__ sym_i,
    const float* __restrict__ chan,
    const float* __restrict__ noise,
    const float* __restrict__ prob,
    float* __restrict__ ws,
    int B, int P, int D, int MU, int cbase, int midT, int rowsPerBlock)
{
    const int tid = threadIdx.x;
    float a0 = 0.f, a1 = 0.f, a2 = 0.f, a3 = 0.f;
    float m0 = 0.f, m1 = 0.f, m2 = 0.f, m3 = 0.f;
    const int st = MU - 1;
    {
        const int gid = blockIdx.x * 256 + tid;
        const int tot = gridDim.x * 256;
        for (int i = gid; i < B; i += tot) {
            const float ch = chan[(size_t)i * st];
            const float cr = ch * sym_r[(size_t)i * st];
            const float ci = ch * sym_i[(size_t)i * st];
            m0 += cr; m1 += cr * cr; m2 += ci; m3 += ci * ci;
        }
    }
    const int row0 = blockIdx.x * rowsPerBlock;
    const int row1 = min(B, row0 + rowsPerBlock);
    const int nISI = MU / 2;

    for (int row = row0; row < row1; ++row) {
        const float* __restrict__ rp = dnn + (size_t)row * P;
        const float bb  = b[row];
        const float bh  = bb * h[row];
        const float vxr = xr[row];
        const float vxi = xi[row];
        const float nz  = INV_SQRT2 * noise[row];
        const float cr0 = bh * vxr, ar_c = nz - vxr;
        const float ci0 = bh * vxi, ai_c = nz - vxi;
        for (int j = tid; j < D; j += 256) {
            float sum7 = 0.f, d0 = 0.f;
            for (int k = 0; k < MU; ++k) {
                const float t = rp[cbase + k * D + j];
                sum7 += t;
                if (k == nISI) d0 = t;
            }
            const float S  = sum7 - d0;
            const float Ar = cr0 * d0 + ar_c;
            const float Ai = ci0 * d0 + ai_c;
            const float bS = bb * S;
            const float pj = prob[midT + j];
            a0 += pj * (Ar * Ar + Ai * Ai);
            a1 += pj * (Ar * bS);
            a2 += pj * (Ai * bS);
            a3 += pj * (bS * bS);
        }
    }

    __shared__ float red[8][4];
    float v[8] = {a0, a1, a2, a3, m0, m1, m2, m3};
    const int wave = tid >> 6, lane = tid & 63;
#pragma unroll
    for (int s = 0; s < 8; ++s) {
        float x = v[s];
#pragma unroll
        for (int off = 32; off > 0; off >>= 1) x += __shfl_down(x, off, 64);
        if (lane == 0) red[s][wave] = x;
    }
    __syncthreads();
    if (tid < 8) {
        float x = red[tid][0] + red[tid][1] + red[tid][2] + red[tid][3];
        ws[(size_t)blockIdx.x * 8 + tid] = x;
    }
}

// ---------------------------------------------------------------------------
// Final: one wave reduces nblk partial vectors and combines.
// ---------------------------------------------------------------------------
__global__ void isi_final(const float* __restrict__ ws,
                          float* __restrict__ out, int nblk, int B)
{
    const int lane = threadIdx.x;      // 64 threads
    float v[8] = {0.f, 0.f, 0.f, 0.f, 0.f, 0.f, 0.f, 0.f};
    for (int i = lane; i < nblk; i += 64) {
        const float* p = ws + (size_t)i * 8;
#pragma unroll
        for (int s = 0; s < 8; ++s) v[s] += p[s];
    }
#pragma unroll
    for (int s = 0; s < 8; ++s) {
        float x = v[s];
#pragma unroll
        for (int off = 32; off > 0; off >>= 1) x += __shfl_down(x, off, 64);
        v[s] = x;
    }
    if (lane == 0) {
        const float invB = 1.0f / (float)B;
        const float P0 = v[0], P1r = v[1], P1i = v[2], P2 = v[3];
        const float m1r = v[4] * invB, m2r = v[5] * invB;
        const float m1i = v[6] * invB, m2i = v[7] * invB;
        out[0] = (P0 + 2.0f * (m1r * P1r + m1i * P1i)
                  + (m2r + m2i) * P2) * invB;
    }
}

extern "C" void kernel_launch(void* const* d_in, const int* in_sizes, int n_in,
                              void* d_out, int out_size, void* d_ws, size_t ws_size,
                              hipStream_t stream)
{
    const float* dnn   = (const float*)d_in[0];
    const float* b     = (const float*)d_in[1];
    const float* h     = (const float*)d_in[2];
    const float* xr    = (const float*)d_in[3];
    const float* xi    = (const float*)d_in[4];
    const float* sym_r = (const float*)d_in[5];
    const float* sym_i = (const float*)d_in[6];
    const float* chan  = (const float*)d_in[7];
    const float* noise = (const float*)d_in[8];
    const float* prob  = (const float*)d_in[9];

    const int B  = in_sizes[1];                // 65536
    const int P  = in_sizes[0] / B;            // 2048
    const int MU = in_sizes[5] / B + 1;        // 7

    const int T     = (P / MU) / 2;            // 146
    const int D     = 2 * T;                   // 292
    const int mid   = P / 2;
    const int midT  = mid - T;                 // 878
    const int cbase = midT - (MU / 2) * D;     // 2

    const int rowsPerBlock = 16;
    const int grid = (B + rowsPerBlock - 1) / rowsPerBlock;   // 4096

    if (P == 2048 && MU == 7 && D == 292 && cbase == 2 && midT == 878 &&
        (B % rowsPerBlock) == 0) {
        isi_main_fast<<<grid, 320, 0, stream>>>(
            dnn, b, h, xr, xi, sym_r, sym_i, chan, noise, prob,
            (float*)d_ws, B, rowsPerBlock);
    } else {
        isi_main_generic<<<grid, 256, 0, stream>>>(
            dnn, b, h, xr, xi, sym_r, sym_i, chan, noise, prob,
            (float*)d_ws, B, P, D, MU, cbase, midT, rowsPerBlock);
    }
    isi_final<<<1, 64, 0, stream>>>((const float*)d_ws, (float*)d_out, grid, B);
}